// Round 5
// baseline (548.444 us; speedup 1.0000x reference)
//
#include <hip/hip_runtime.h>

#define NN 4096
#define KK 48
#define CC 128
#define EC 384
#define DD 512
#define HH 512

typedef short bf16x8 __attribute__((ext_vector_type(8)));
typedef float f32x4 __attribute__((ext_vector_type(4)));
typedef unsigned int u32;

typedef const __attribute__((address_space(1))) void* gas1_t;
typedef __attribute__((address_space(3))) void* las3_t;

#define CB() asm volatile("" ::: "memory")

__device__ __forceinline__ u32 pk2(float lo, float hi){
  u32 r; asm("v_cvt_pk_bf16_f32 %0, %1, %2" : "=v"(r) : "v"(lo), "v"(hi)); return r;
}
__device__ __forceinline__ unsigned short f2bf(float x){ return (unsigned short)pk2(x,x); }
__device__ __forceinline__ bf16x8 pack8(f32x4 a, f32x4 b){
  union { u32 w[4]; bf16x8 v; } u;
  u.w[0]=pk2(a[0],a[1]); u.w[1]=pk2(a[2],a[3]);
  u.w[2]=pk2(b[0],b[1]); u.w[3]=pk2(b[2],b[3]);
  return u.v;
}
__device__ __forceinline__ float gelu_f(float x){
  float s = 1.5957691216057308f*(x + 0.044715f*x*x*x);
  float e = __expf(s);
  return 0.5f*x*(1.f + (1.f - 2.f/(e+1.f)));
}

// ---------------- weight fp32 -> bf16 conversion ---------------------------------
__global__ void cvt_kernel(const float* __restrict__ W1, const float* __restrict__ W2,
                           const float* __restrict__ W3, const float* __restrict__ Wd1,
                           const float* __restrict__ Wd2, unsigned short* __restrict__ o){
  int i = blockIdx.x*256 + threadIdx.x;   // grid 896*256 = 229376
  float v;
  if      (i <  65536) v = W1[i];
  else if (i <  81920) v = W2[i-65536];
  else if (i <  98304) v = W3[i-81920];
  else if (i < 163840) v = Wd1[i-98304];
  else                 v = Wd2[i-163840];
  o[i] = f2bf(v);
}

// ---------------- node-part hoist: Y = nodef @ W1_node^T + b1 (4096x128) ---------
__global__ __launch_bounds__(256, 4) void node_kernel(
    const float* __restrict__ nodef, const unsigned short* __restrict__ W1b,
    const float* __restrict__ b1, float* __restrict__ Y)
{
  const int tid  = threadIdx.x;
  const int lane = tid & 63;
  const int wid  = tid >> 6;
  const int l15  = lane & 15;
  const int lg   = lane >> 4;
  const int lg8  = lg*8;
  const int rowb = blockIdx.x*64 + wid*16;

  f32x4 acc[8];
  #pragma unroll
  for (int nt=0; nt<8; ++nt) acc[nt] = (f32x4){0.f,0.f,0.f,0.f};

  const float* arow = nodef + (size_t)(rowb + l15)*CC;
  #pragma unroll
  for (int ks=0; ks<4; ++ks){
    const int k0 = ks*32;
    bf16x8 af = pack8(*(const f32x4*)(arow + k0 + lg8), *(const f32x4*)(arow + k0 + lg8 + 4));
    #pragma unroll
    for (int nt=0; nt<8; ++nt){
      bf16x8 bf_ = *(const bf16x8*)(W1b + (size_t)(nt*16 + l15)*DD + k0 + lg8);
      acc[nt] = __builtin_amdgcn_mfma_f32_16x16x32_bf16(af, bf_, acc[nt], 0,0,0);
    }
  }
  #pragma unroll
  for (int nt=0; nt<8; ++nt){
    const int c = nt*16 + l15;
    const float bb = b1[c];
    #pragma unroll
    for (int j=0; j<4; ++j)
      Y[(size_t)(rowb + lg*4 + j)*CC + c] = acc[nt][j] + bb;
  }
}

// ---------------- fused message MLP + aggregation + LN/dense/LN ------------------
// block = 256 threads (4 waves: 2 M x 2 N), 2 nodes (96 edge rows).
// GEMM1 A staged via global_load_lds, 3-buffer, counted vmcnt, raw s_barrier.
__global__ __launch_bounds__(256, 2) void msg_kernel(
    const float* __restrict__ nodef, const float* __restrict__ edgef,
    const float* __restrict__ attn, const float* __restrict__ Y,
    const unsigned short* __restrict__ W1b,
    const unsigned short* __restrict__ W2b, const float* __restrict__ b2,
    const unsigned short* __restrict__ W3b, const float* __restrict__ b3,
    const float* __restrict__ g1v, const float* __restrict__ be1,
    const unsigned short* __restrict__ Wd1b, const float* __restrict__ bd1,
    const unsigned short* __restrict__ Wd2b, const float* __restrict__ bd2,
    const float* __restrict__ g2v, const float* __restrict__ be2,
    const float* __restrict__ maskv, float* __restrict__ out)
{
  // A tiles: 3 x [96 rows][32 floats] = 36864 B, row-major packed, slot-XOR swizzle.
  __shared__ __attribute__((aligned(16))) char SA[36864];
  __shared__ __attribute__((aligned(16))) unsigned short H[96][136];  // 26112 B

  float (*Abuf)[96*32] = (float(*)[96*32])SA;
  // post-phase overlays (A dead by then):
  unsigned short (*xlnB)[136] = (unsigned short(*)[136])SA;          // [16][136] rows 2..15 garbage
  float* xlnF = (float*)(SA + 4352);                                 // [2][128]
  float* x1s  = (float*)(SA + 5376);                                 // [2][128]
  unsigned short (*Hd)[520] = (unsigned short(*)[520])(SA + 6400);   // [16][520] rows 2..15 garbage
  float* x2s  = (float*)(SA + 23040);                                // [2][128]

  const int tid  = threadIdx.x;
  const int lane = tid & 63;
  const int wid  = tid >> 6;
  const int wm   = wid & 1;
  const int wn   = wid >> 1;
  const int l15  = lane & 15;
  const int lg   = lane >> 4;
  const int lg8  = lg*8;
  const int node0 = blockIdx.x*2;
  const int node  = node0 + wm;
  const int colb  = wn*64;

  // ---- DMA source mapping: chunk c = wid*3+i covers tile rows 8c..8c+7 ----------
  // lane l: r = c*8 + (l>>3); LDS slot sigma = l&7; source slot s = sigma ^ (r&7).
  const float* gsrc = edgef + (size_t)node0*KK*EC;
  int dma_r[3], dma_s4[3];
  #pragma unroll
  for (int i=0;i<3;++i){
    int c = wid*3 + i;
    int r = c*8 + (lane>>3);
    int s = (lane&7) ^ (r&7);
    dma_r[i] = r;
    dma_s4[i] = s*4;
  }

#define STAGE(B_, T_)                                                              \
  { _Pragma("unroll")                                                              \
    for (int i_=0;i_<3;++i_){                                                      \
      __builtin_amdgcn_global_load_lds(                                            \
        (gas1_t)(gsrc + (size_t)dma_r[i_]*EC + (T_)*32 + dma_s4[i_]),              \
        (las3_t)&Abuf[B_][(wid*3+i_)*256], 16, 0, 0);                              \
    } }

  // ---- acc init from Y (b1 folded in) ----
  float yv[4];
  #pragma unroll
  for (int nt=0; nt<4; ++nt)
    yv[nt] = Y[(size_t)node*CC + colb + nt*16 + l15];

  f32x4 acc[3][4];
  #pragma unroll
  for (int mt=0; mt<3; ++mt)
    #pragma unroll
    for (int nt=0; nt<4; ++nt)
      #pragma unroll
      for (int j=0; j<4; ++j) acc[mt][nt][j] = yv[nt];

  CB();
  // ---- prologue: B(0) prefetch, stage tiles 0,1 ----
  bf16x8 bC[4], bN[4];
  #pragma unroll
  for (int nt=0; nt<4; ++nt)
    bC[nt] = *(const bf16x8*)(W1b + (size_t)(colb + nt*16 + l15)*DD + CC + lg8);
  CB();
  STAGE(0, 0); CB();
  STAGE(1, 1); CB();

  // ---- GEMM1 K-loop: 12 tiles of K=32 over the edge part ----
  #pragma unroll
  for (int t=0; t<12; ++t){
    const int cur = t % 3;
    if (t < 11){
      #pragma unroll
      for (int nt=0; nt<4; ++nt)
        bN[nt] = *(const bf16x8*)(W1b + (size_t)(colb + nt*16 + l15)*DD + CC + (t+1)*32 + lg8);
    }
    CB();
    if (t < 11) asm volatile("s_waitcnt vmcnt(7)" ::: "memory");
    else        asm volatile("s_waitcnt vmcnt(0)" ::: "memory");
    __builtin_amdgcn_s_barrier();
    CB();
    if (t+2 < 12){ STAGE((t+2)%3, t+2); }   // refill buffer consumed at t-1 (all waves past barrier)
    CB();
    // consume tile t: swizzled ds_read + cvt_pk pack
    bf16x8 a_[3];
    #pragma unroll
    for (int mt=0; mt<3; ++mt){
      const int r  = wm*48 + mt*16 + l15;
      const int s0 = (2*lg)   ^ (r&7);
      const int s1 = (2*lg+1) ^ (r&7);
      f32x4 lo = *(const f32x4*)&Abuf[cur][r*32 + s0*4];
      f32x4 hi = *(const f32x4*)&Abuf[cur][r*32 + s1*4];
      a_[mt] = pack8(lo, hi);
    }
    #pragma unroll
    for (int mt=0; mt<3; ++mt)
      #pragma unroll
      for (int nt=0; nt<4; ++nt)
        acc[mt][nt] = __builtin_amdgcn_mfma_f32_16x16x32_bf16(a_[mt], bC[nt], acc[mt][nt], 0,0,0);
    #pragma unroll
    for (int nt=0; nt<4; ++nt) bC[nt] = bN[nt];
  }

  // epilogue 1: gelu -> H (bf16)
  #pragma unroll
  for (int nt=0; nt<4; ++nt){
    const int c = colb + nt*16 + l15;
    #pragma unroll
    for (int mt=0; mt<3; ++mt){
      const int r0 = wm*48 + mt*16 + lg*4;
      #pragma unroll
      for (int j=0; j<4; ++j)
        H[r0+j][c] = f2bf(gelu_f(acc[mt][nt][j]));
    }
  }
  __syncthreads();

  // ---- GEMM2: (96x128) x W2^T ----
  f32x4 a2[3][4];
  #pragma unroll
  for (int mt=0; mt<3; ++mt)
    #pragma unroll
    for (int nt=0; nt<4; ++nt) a2[mt][nt] = (f32x4){0.f,0.f,0.f,0.f};

  #pragma unroll
  for (int ks=0; ks<4; ++ks){
    const int k0 = ks*32;
    bf16x8 bf_[4], af_[3];
    #pragma unroll
    for (int nt=0; nt<4; ++nt)
      bf_[nt] = *(const bf16x8*)(W2b + (size_t)(colb + nt*16 + l15)*CC + k0 + lg8);
    #pragma unroll
    for (int mt=0; mt<3; ++mt)
      af_[mt] = *(const bf16x8*)&H[wm*48 + mt*16 + l15][k0 + lg8];
    #pragma unroll
    for (int mt=0; mt<3; ++mt)
      #pragma unroll
      for (int nt=0; nt<4; ++nt)
        a2[mt][nt] = __builtin_amdgcn_mfma_f32_16x16x32_bf16(af_[mt], bf_[nt], a2[mt][nt], 0,0,0);
  }
  __syncthreads();   // all GEMM2 reads done before H overwritten

  #pragma unroll
  for (int nt=0; nt<4; ++nt){
    const int c = colb + nt*16 + l15;
    const float bb = b2[c];
    #pragma unroll
    for (int mt=0; mt<3; ++mt){
      const int r0 = wm*48 + mt*16 + lg*4;
      #pragma unroll
      for (int j=0; j<4; ++j)
        H[r0+j][c] = f2bf(gelu_f(a2[mt][nt][j] + bb));
    }
  }
  __syncthreads();

  // ---- GEMM3: (96x128) x W3^T (linear out) ----
  f32x4 a3[3][4];
  #pragma unroll
  for (int mt=0; mt<3; ++mt)
    #pragma unroll
    for (int nt=0; nt<4; ++nt) a3[mt][nt] = (f32x4){0.f,0.f,0.f,0.f};

  #pragma unroll
  for (int ks=0; ks<4; ++ks){
    const int k0 = ks*32;
    bf16x8 bf_[4], af_[3];
    #pragma unroll
    for (int nt=0; nt<4; ++nt)
      bf_[nt] = *(const bf16x8*)(W3b + (size_t)(colb + nt*16 + l15)*CC + k0 + lg8);
    #pragma unroll
    for (int mt=0; mt<3; ++mt)
      af_[mt] = *(const bf16x8*)&H[wm*48 + mt*16 + l15][k0 + lg8];
    #pragma unroll
    for (int mt=0; mt<3; ++mt)
      #pragma unroll
      for (int nt=0; nt<4; ++nt)
        a3[mt][nt] = __builtin_amdgcn_mfma_f32_16x16x32_bf16(af_[mt], bf_[nt], a3[mt][nt], 0,0,0);
  }

  // ---- aggregation -> x1 (LDS only; no global round-trip) ----
  float av[3][4];
  #pragma unroll
  for (int mt=0; mt<3; ++mt)
    #pragma unroll
    for (int j=0; j<4; ++j)
      av[mt][j] = attn[(size_t)node*KK + mt*16 + lg*4 + j];

  float tt[4];
  #pragma unroll
  for (int nt=0; nt<4; ++nt){
    const int c = colb + nt*16 + l15;
    const float bb = b3[c];
    float t = 0.f;
    #pragma unroll
    for (int mt=0; mt<3; ++mt)
      #pragma unroll
      for (int j=0; j<4; ++j)
        t += (a3[mt][nt][j] + bb) * av[mt][j];
    t += __shfl_xor(t, 16, 64);
    t += __shfl_xor(t, 32, 64);
    tt[nt] = t;
  }
  if (lg == 0){
    #pragma unroll
    for (int nt=0; nt<4; ++nt){
      const int c = colb + nt*16 + l15;
      x1s[wm*128 + c] = nodef[(size_t)node*CC + c] + tt[nt]*(1.0f/30.0f);
    }
  }
  __syncthreads();

  // ---- LN1 (waves 0,1: one node each) ----
  if (wid < 2){
    float v0 = x1s[wid*128 + lane];
    float v1 = x1s[wid*128 + 64 + lane];
    float sm = v0+v1, sq = v0*v0+v1*v1;
    #pragma unroll
    for (int d=1; d<64; d<<=1){ sm += __shfl_xor(sm,d,64); sq += __shfl_xor(sq,d,64); }
    const float mu = sm*(1.f/128.f);
    const float rs = rsqrtf(sq*(1.f/128.f) - mu*mu + 1e-5f);
    float y0 = (v0-mu)*rs*g1v[lane]    + be1[lane];
    float y1 = (v1-mu)*rs*g1v[lane+64] + be1[lane+64];
    xlnF[wid*128 + lane]      = y0;
    xlnF[wid*128 + 64 + lane] = y1;
    xlnB[wid][lane]      = f2bf(y0);
    xlnB[wid][lane + 64] = f2bf(y1);
  }
  __syncthreads();

  // ---- dense layer 1: M=16 MFMA (rows 2..15 garbage, ignored) ----
  f32x4 d1acc[8];
  #pragma unroll
  for (int nt=0; nt<8; ++nt) d1acc[nt] = (f32x4){0.f,0.f,0.f,0.f};
  #pragma unroll
  for (int ks=0; ks<4; ++ks){
    const int k0 = ks*32;
    bf16x8 af = *(const bf16x8*)&xlnB[l15][k0 + lg8];
    #pragma unroll
    for (int nt=0; nt<8; ++nt){
      const int h = wid*128 + nt*16 + l15;
      bf16x8 bf_ = *(const bf16x8*)(Wd1b + (size_t)h*CC + k0 + lg8);
      d1acc[nt] = __builtin_amdgcn_mfma_f32_16x16x32_bf16(af, bf_, d1acc[nt], 0,0,0);
    }
  }
  if (lg == 0){
    #pragma unroll
    for (int nt=0; nt<8; ++nt){
      const int h = wid*128 + nt*16 + l15;
      const float bb = bd1[h];
      Hd[0][h] = f2bf(gelu_f(d1acc[nt][0] + bb));
      Hd[1][h] = f2bf(gelu_f(d1acc[nt][1] + bb));
    }
  }
  __syncthreads();

  // ---- dense layer 2 + residual ----
  f32x4 d2acc[2];
  #pragma unroll
  for (int nt=0; nt<2; ++nt) d2acc[nt] = (f32x4){0.f,0.f,0.f,0.f};
  #pragma unroll
  for (int ks=0; ks<16; ++ks){
    const int k0 = ks*32;
    bf16x8 af = *(const bf16x8*)&Hd[l15][k0 + lg8];
    #pragma unroll
    for (int nt=0; nt<2; ++nt){
      const int c = wid*32 + nt*16 + l15;
      bf16x8 bf_ = *(const bf16x8*)(Wd2b + (size_t)c*HH + k0 + lg8);
      d2acc[nt] = __builtin_amdgcn_mfma_f32_16x16x32_bf16(af, bf_, d2acc[nt], 0,0,0);
    }
  }
  if (lg == 0){
    #pragma unroll
    for (int nt=0; nt<2; ++nt){
      const int c = wid*32 + nt*16 + l15;
      const float bb = bd2[c];
      x2s[0*128 + c] = xlnF[0*128 + c] + d2acc[nt][0] + bb;
      x2s[1*128 + c] = xlnF[1*128 + c] + d2acc[nt][1] + bb;
    }
  }
  __syncthreads();

  // ---- LN2 + mask + store ----
  if (wid < 2){
    const int gn = node0 + wid;
    float v0 = x2s[wid*128 + lane];
    float v1 = x2s[wid*128 + 64 + lane];
    float sm = v0+v1, sq = v0*v0+v1*v1;
    #pragma unroll
    for (int d=1; d<64; d<<=1){ sm += __shfl_xor(sm,d,64); sq += __shfl_xor(sq,d,64); }
    const float mu = sm*(1.f/128.f);
    const float rs = rsqrtf(sq*(1.f/128.f) - mu*mu + 1e-5f);
    const float mk = maskv[gn];
    out[(size_t)gn*CC + lane]      = mk*((v0-mu)*rs*g2v[lane]    + be2[lane]);
    out[(size_t)gn*CC + 64 + lane] = mk*((v1-mu)*rs*g2v[lane+64] + be2[lane+64]);
  }
#undef STAGE
}

extern "C" void kernel_launch(void* const* d_in, const int* in_sizes, int n_in,
                              void* d_out, int out_size, void* d_ws, size_t ws_size,
                              hipStream_t stream)
{
  (void)in_sizes; (void)n_in; (void)out_size; (void)ws_size;

  const float* nodef = (const float*)d_in[0];
  const float* edgef = (const float*)d_in[1];
  const float* mask  = (const float*)d_in[2];
  const float* attn  = (const float*)d_in[3];
  const float* W_m1  = (const float*)d_in[4];
  const float* b_m1  = (const float*)d_in[5];
  const float* W_m2  = (const float*)d_in[6];
  const float* b_m2  = (const float*)d_in[7];
  const float* W_m3  = (const float*)d_in[8];
  const float* b_m3  = (const float*)d_in[9];
  const float* g1    = (const float*)d_in[10];
  const float* be1   = (const float*)d_in[11];
  const float* W_d1  = (const float*)d_in[12];
  const float* b_d1  = (const float*)d_in[13];
  const float* W_d2  = (const float*)d_in[14];
  const float* b_d2  = (const float*)d_in[15];
  const float* g2    = (const float*)d_in[16];
  const float* be2   = (const float*)d_in[17];

  // ws layout: [0, 458752) bf16 weights; [458752, 2555904) Y f32
  unsigned short* wsb  = (unsigned short*)d_ws;
  unsigned short* W1b  = wsb;
  unsigned short* W2b  = wsb + 65536;
  unsigned short* W3b  = wsb + 81920;
  unsigned short* Wd1b = wsb + 98304;
  unsigned short* Wd2b = wsb + 163840;
  float* Y = (float*)((char*)d_ws + 458752);

  cvt_kernel<<<896, 256, 0, stream>>>(W_m1, W_m2, W_m3, W_d1, W_d2, wsb);
  node_kernel<<<64, 256, 0, stream>>>(nodef, W1b, b_m1, Y);
  msg_kernel<<<2048, 256, 0, stream>>>(nodef, edgef, attn, Y,
                                       W1b, W2b, b_m2, W3b, b_m3,
                                       g1, be1, Wd1b, b_d1, Wd2b, b_d2,
                                       g2, be2, mask, (float*)d_out);
}